// Round 11
// baseline (641.039 us; speedup 1.0000x reference)
//
#include <hip/hip_runtime.h>

typedef __attribute__((ext_vector_type(8))) short bf16x8;
typedef __attribute__((ext_vector_type(4))) float f32x4;
typedef __attribute__((ext_vector_type(16))) float f32x16;

#define NBLK 512
#define NTHR 512    // 8 waves; 1 block/CU (128 KB LDS)
#define DOUT 128

__device__ __forceinline__ unsigned short bf_rne(float x) {
  unsigned u = __builtin_bit_cast(unsigned, x);
  return (unsigned short)((u + 0x7FFFu + ((u >> 16) & 1u)) >> 16);
}
// fp32 -> bf16 hi (truncate) + bf16 lo (RNE of residual); x ~ hi+lo to ~2^-15 rel
__device__ __forceinline__ void split2(float x, short& hi, short& lo) {
  unsigned u = __builtin_bit_cast(unsigned, x);
  float hf = __builtin_bit_cast(float, u & 0xFFFF0000u);
  hi = (short)(unsigned short)(u >> 16);
  lo = (short)bf_rne(x - hf);
}

// R11: 32x32x16 MFMA halves LDS frag traffic per FLOP (R10's binding pipe:
// ~110us/CU of ds_read incl. 8-way conflicts from a broken swizzle).
//  - W (masked, hi/lo bf16 split) in LDS, FRAG-LINEAR layout: frag f at
//    wl[f*512 + lane*8] (hi), +32768 shorts (lo). Consecutive lanes read
//    consecutive 16B -> 2-way max = free. R8 measured 0 conflicts. NO swizzle.
//  - x streamed through regs: depth-4 slots (ks&3, static in unrolled loop),
//    refilled 4 k-steps (~full MFMA phase) ahead. Zero main-loop barriers.
//  - (512,2): the only proven non-spilling config (R8:120V, R10:104V ok;
//    (512,8)/(1024,*) -> forced 32/64V + GB-scale scratch; R9 dyn-loop: 128V+spill).
//  - A=W (rows of D = out cols), B=x (cols of D = batch rows).
//    D layout (m74/m101): col=lane&31, row=(reg&3)+8*(reg>>2)+4*(lane>>5)
//    -> per (ct, reg-group g): f32x4 store at out col ct*32+8g+4*(l>>5).
__global__ __launch_bounds__(NTHR, 2)
void dagmm(const float* __restrict__ x0, const float* __restrict__ x1,
           const float* __restrict__ w0, const float* __restrict__ w1,
           const float* __restrict__ m0, const float* __restrict__ m1,
           float* __restrict__ out)
{
  __shared__ short wl[65536];   // 64 frags x 1 KB hi  |  +64 KB lo

  const int t   = threadIdx.x;
  const int l   = t & 63;
  const int w   = t >> 6;       // wave 0..7
  const int l31 = l & 31;
  const int lh  = l >> 5;       // 0/1

  // ---------- stage masked, hi/lo-split W into LDS (once) ----------
  // frag f = ct*16 + ks (ct: 32-col tile 0..3, ks: K=16 step 0..15)
  // lane cl holds W[col = ct*32 + (cl&31)][k = ks*16 + (cl>>5)*8 + j], j=0..7
#pragma unroll
  for (int rep = 0; rep < 8; ++rep) {
    const int chunk = rep * 512 + t;           // 4096 = 64 frags * 64 lanes
    const int cl = chunk & 63;
    const int f  = chunk >> 6;                 // 0..63
    const int ks = f & 15, ct = f >> 4;
    const int col = ct * 32 + (cl & 31);
    const int k0  = ks * 16 + ((cl >> 5) << 3);    // 0..248, never straddles 128
    const float* wp = (k0 < 128) ? (w0 + col * 128 + k0) : (w1 + col * 128 + (k0 - 128));
    const float* mp = (k0 < 128) ? (m0 + col * 128 + k0) : (m1 + col * 128 + (k0 - 128));
    float4 wa = *(const float4*)wp, wb = *(const float4*)(wp + 4);
    float4 ma = *(const float4*)mp, mb = *(const float4*)(mp + 4);
    float v[8] = {wa.x*ma.x, wa.y*ma.y, wa.z*ma.z, wa.w*ma.w,
                  wb.x*mb.x, wb.y*mb.y, wb.z*mb.z, wb.w*mb.w};
    bf16x8 hv, lv;
#pragma unroll
    for (int j = 0; j < 8; ++j) { short h, lo2; split2(v[j], h, lo2); hv[j] = h; lv[j] = lo2; }
    *(bf16x8*)&wl[f * 512 + cl * 8]         = hv;
    *(bf16x8*)&wl[f * 512 + cl * 8 + 32768] = lv;
  }
  __syncthreads();   // only barrier in the kernel

  const int gw = blockIdx.x * 8 + w;          // owns rows [gw*128, gw*128+128)
  const size_t rowbase = (size_t)gw * 128;

  // x B-frag address (tile tt 0..3, k-step ks 0..15):
  // lane reads 8 floats at (row = rowbase + tt*32 + l31, k = ks*16 + lh*8)
  auto xaddr = [&](int tt, int ks) -> const float* {
    const int k = ks * 16 + lh * 8;           // never straddles 128
    const float* bp = (k < 128) ? (x0 + k) : (x1 + (k - 128));
    return bp + (rowbase + tt * 32 + l31) * 128;
  };

  // depth-4 prefetch slots (8 VGPRs each), statically indexed by ks&3
  float4 pf[4][2];
#pragma unroll
  for (int s = 0; s < 4; ++s) {
    const float* p = xaddr(0, s);
    pf[s][0] = *(const float4*)p;
    pf[s][1] = *(const float4*)(p + 4);
  }

  for (int tt = 0; tt < 4; ++tt) {
    f32x16 acc[4];
#pragma unroll
    for (int ct = 0; ct < 4; ++ct)
#pragma unroll
      for (int r = 0; r < 16; ++r) acc[ct][r] = 0.f;

#pragma unroll
    for (int ks = 0; ks < 16; ++ks) {
      const int sl = ks & 3;                  // static after unroll
      float4 c0 = pf[sl][0], c1 = pf[sl][1];

      // refill slot for step +4 (16%4==0 keeps slot phase across tiles)
      if (ks < 12) {                          // static: same tile
        const float* np = xaddr(tt, ks + 4);
        pf[sl][0] = *(const float4*)np;
        pf[sl][1] = *(const float4*)(np + 4);
      } else if (tt < 3) {                    // wave-uniform: next tile
        const float* np = xaddr(tt + 1, ks - 12);
        pf[sl][0] = *(const float4*)np;
        pf[sl][1] = *(const float4*)(np + 4);
      }

      float vv[8] = {c0.x, c0.y, c0.z, c0.w, c1.x, c1.y, c1.z, c1.w};
      bf16x8 xh, xl;
#pragma unroll
      for (int j = 0; j < 8; ++j) { short h, lo2; split2(vv[j], h, lo2); xh[j] = h; xl[j] = lo2; }

#pragma unroll
      for (int ct = 0; ct < 4; ++ct) {
        const int bi = (ct * 16 + ks) * 512 + l * 8;
        bf16x8 wh  = *(const bf16x8*)&wl[bi];
        bf16x8 wlo = *(const bf16x8*)&wl[bi + 32768];
        // W ~ wh+wlo, X ~ xh+xl: wh*xh + wh*xl + wlo*xh (drop wlo*xl ~2^-30)
        acc[ct] = __builtin_amdgcn_mfma_f32_32x32x16_bf16(wh,  xh, acc[ct], 0, 0, 0);
        acc[ct] = __builtin_amdgcn_mfma_f32_32x32x16_bf16(wh,  xl, acc[ct], 0, 0, 0);
        acc[ct] = __builtin_amdgcn_mfma_f32_32x32x16_bf16(wlo, xh, acc[ct], 0, 0, 0);
      }
    }

    // D: col(l31) = batch row, row = (reg&3) + 8*(reg>>2) + 4*lh = out col
    const size_t row = rowbase + tt * 32 + l31;
#pragma unroll
    for (int ct = 0; ct < 4; ++ct)
#pragma unroll
      for (int g = 0; g < 4; ++g) {
        f32x4 v = {acc[ct][g*4+0], acc[ct][g*4+1], acc[ct][g*4+2], acc[ct][g*4+3]};
        *(f32x4*)&out[row * DOUT + ct * 32 + g * 8 + lh * 4] = v;
      }
  }
}

extern "C" void kernel_launch(void* const* d_in, const int* in_sizes, int n_in,
                              void* d_out, int out_size, void* d_ws, size_t ws_size,
                              hipStream_t stream) {
  const float* x0 = (const float*)d_in[0];
  const float* x1 = (const float*)d_in[1];
  const float* w0 = (const float*)d_in[2];
  const float* w1 = (const float*)d_in[3];
  const float* m0 = (const float*)d_in[4];
  const float* m1 = (const float*)d_in[5];
  dagmm<<<NBLK, NTHR, 0, stream>>>(x0, x1, w0, w1, m0, m1, (float*)d_out);
}

// Round 12
// 368.183 us; speedup vs baseline: 1.7411x; 1.7411x over previous
//
#include <hip/hip_runtime.h>

typedef __attribute__((ext_vector_type(8))) short bf16x8;
typedef __attribute__((ext_vector_type(4))) float f32x4;
typedef __attribute__((ext_vector_type(16))) float f32x16;

#define NBLK 512
#define NTHR 512    // 8 waves = 4 row-groups x 2 col-pairs; 1 block/CU (128 KB LDS)
#define DOUT 128

__device__ __forceinline__ unsigned short bf_rne(float x) {
  unsigned u = __builtin_bit_cast(unsigned, x);
  return (unsigned short)((u + 0x7FFFu + ((u >> 16) & 1u)) >> 16);
}
// fp32 -> bf16 hi (truncate) + bf16 lo (RNE of residual); x ~ hi+lo to ~2^-15 rel
__device__ __forceinline__ void split2(float x, short& hi, short& lo) {
  unsigned u = __builtin_bit_cast(unsigned, x);
  float hf = __builtin_bit_cast(float, u & 0xFFFF0000u);
  hi = (short)(unsigned short)(u >> 16);
  lo = (short)bf_rne(x - hf);
}

// R12 = R11 minus the spill: 32x32x16 MFMA (2 LDS reads / 3 MFMAs -> 41us/CU
// LDS pipe, conflict-free frag-linear W layout, R8/R11-measured 0 conflicts),
// x register-streamed depth-4, zero main-loop barriers, (512,2) launch.
// Spill fix: acc[2] f32x16 (32 regs) instead of R11's acc[4] (64) — each wave
// owns 32 rows x 64 cols; the two col-pair waves re-load the same x tile
// (2x issue, L1/L2-absorbed; HBM compulsory unchanged).
// Register law (R1-R11): cap = 256/(2nd arg), only (512,2)->128 fits this body;
// R3/R6/R9/R11 all died to spill (FETCH GB-scale = the signature).
__global__ __launch_bounds__(NTHR, 2)
void dagmm(const float* __restrict__ x0, const float* __restrict__ x1,
           const float* __restrict__ w0, const float* __restrict__ w1,
           const float* __restrict__ m0, const float* __restrict__ m1,
           float* __restrict__ out)
{
  __shared__ short wl[65536];   // 64 frags x 1 KB hi  |  +64 KB lo

  const int t   = threadIdx.x;
  const int l   = t & 63;
  const int w   = t >> 6;       // wave 0..7
  const int l31 = l & 31;
  const int lh  = l >> 5;       // 0/1
  const int rbi = w >> 1;       // row-group 0..3 (32 rows each within a sweep)
  const int cp  = w & 1;        // col-pair: cols [cp*64, cp*64+64)

  // ---------- stage masked, hi/lo-split W into LDS (once; R11-verified) ----
  // frag f = ct*16 + ks; lane cl holds W[col=ct*32+(cl&31)][k=ks*16+(cl>>5)*8+j]
#pragma unroll
  for (int rep = 0; rep < 8; ++rep) {
    const int chunk = rep * 512 + t;           // 4096 = 64 frags * 64 lanes
    const int cl = chunk & 63;
    const int f  = chunk >> 6;                 // 0..63
    const int ks = f & 15, ct = f >> 4;
    const int col = ct * 32 + (cl & 31);
    const int k0  = ks * 16 + ((cl >> 5) << 3);    // 0..248, never straddles 128
    const float* wp = (k0 < 128) ? (w0 + col * 128 + k0) : (w1 + col * 128 + (k0 - 128));
    const float* mp = (k0 < 128) ? (m0 + col * 128 + k0) : (m1 + col * 128 + (k0 - 128));
    float4 wa = *(const float4*)wp, wb = *(const float4*)(wp + 4);
    float4 ma = *(const float4*)mp, mb = *(const float4*)(mp + 4);
    float v[8] = {wa.x*ma.x, wa.y*ma.y, wa.z*ma.z, wa.w*ma.w,
                  wb.x*mb.x, wb.y*mb.y, wb.z*mb.z, wb.w*mb.w};
    bf16x8 hv, lv;
#pragma unroll
    for (int j = 0; j < 8; ++j) { short h, lo2; split2(v[j], h, lo2); hv[j] = h; lv[j] = lo2; }
    *(bf16x8*)&wl[f * 512 + cl * 8]         = hv;
    *(bf16x8*)&wl[f * 512 + cl * 8 + 32768] = lv;
  }
  __syncthreads();   // only barrier in the kernel

  const size_t Rbase = (size_t)blockIdx.x * 1024;   // block owns 1024 rows

  // x B-frag (32x32x16): lane reads 8 floats at
  // (row = Rbase + sw*128 + rbi*32 + l31, k = ks*16 + lh*8)
  auto xaddr = [&](int sw, int ks) -> const float* {
    const int k = ks * 16 + lh * 8;           // never straddles 128
    const float* bp = (k < 128) ? (x0 + k) : (x1 + (k - 128));
    return bp + (Rbase + sw * 128 + rbi * 32 + l31) * 128;
  };

  // depth-4 prefetch slots (8 VGPRs each), statically indexed by ks&3
  float4 pf[4][2];
#pragma unroll
  for (int s = 0; s < 4; ++s) {
    const float* p = xaddr(0, s);
    pf[s][0] = *(const float4*)p;
    pf[s][1] = *(const float4*)(p + 4);
  }

  for (int sw = 0; sw < 8; ++sw) {            // 8 sweeps x 128 rows = 1024
    f32x16 acc[2];
#pragma unroll
    for (int c = 0; c < 2; ++c)
#pragma unroll
      for (int r = 0; r < 16; ++r) acc[c][r] = 0.f;

#pragma unroll
    for (int ks = 0; ks < 16; ++ks) {
      const int sl = ks & 3;                  // static after unroll
      float4 c0 = pf[sl][0], c1 = pf[sl][1];

      // refill slot for step +4 (16%4==0 keeps slot phase across sweeps)
      if (ks < 12) {                          // static: same sweep
        const float* np = xaddr(sw, ks + 4);
        pf[sl][0] = *(const float4*)np;
        pf[sl][1] = *(const float4*)(np + 4);
      } else if (sw < 7) {                    // wave-uniform: next sweep
        const float* np = xaddr(sw + 1, ks - 12);
        pf[sl][0] = *(const float4*)np;
        pf[sl][1] = *(const float4*)(np + 4);
      }

      float vv[8] = {c0.x, c0.y, c0.z, c0.w, c1.x, c1.y, c1.z, c1.w};
      bf16x8 xh, xl;
#pragma unroll
      for (int j = 0; j < 8; ++j) { short h, lo2; split2(vv[j], h, lo2); xh[j] = h; xl[j] = lo2; }

#pragma unroll
      for (int c = 0; c < 2; ++c) {
        const int ct = cp * 2 + c;
        const int bi = (ct * 16 + ks) * 512 + l * 8;
        bf16x8 wh  = *(const bf16x8*)&wl[bi];
        bf16x8 wlo = *(const bf16x8*)&wl[bi + 32768];
        // W ~ wh+wlo, X ~ xh+xl: wh*xh + wh*xl + wlo*xh (drop wlo*xl ~2^-30)
        acc[c] = __builtin_amdgcn_mfma_f32_32x32x16_bf16(wh,  xh, acc[c], 0, 0, 0);
        acc[c] = __builtin_amdgcn_mfma_f32_32x32x16_bf16(wh,  xl, acc[c], 0, 0, 0);
        acc[c] = __builtin_amdgcn_mfma_f32_32x32x16_bf16(wlo, xh, acc[c], 0, 0, 0);
      }
    }

    // D: col(l31) = batch row; out col = ct*32 + (reg&3)+8*(reg>>2)+4*lh
    // (m74/m101 mapping; R11 passed refcheck with it)
    const size_t row = Rbase + sw * 128 + rbi * 32 + l31;
#pragma unroll
    for (int c = 0; c < 2; ++c) {
      const int ct = cp * 2 + c;
#pragma unroll
      for (int g = 0; g < 4; ++g) {
        f32x4 v = {acc[c][g*4+0], acc[c][g*4+1], acc[c][g*4+2], acc[c][g*4+3]};
        *(f32x4*)&out[row * DOUT + ct * 32 + g * 8 + lh * 4] = v;
      }
    }
  }
}

extern "C" void kernel_launch(void* const* d_in, const int* in_sizes, int n_in,
                              void* d_out, int out_size, void* d_ws, size_t ws_size,
                              hipStream_t stream) {
  const float* x0 = (const float*)d_in[0];
  const float* x1 = (const float*)d_in[1];
  const float* w0 = (const float*)d_in[2];
  const float* w1 = (const float*)d_in[3];
  const float* m0 = (const float*)d_in[4];
  const float* m1 = (const float*)d_in[5];
  dagmm<<<NBLK, NTHR, 0, stream>>>(x0, x1, w0, w1, m0, m1, (float*)d_out);
}

// Round 13
// 175.494 us; speedup vs baseline: 3.6528x; 2.0980x over previous
//
#include <hip/hip_runtime.h>

typedef __attribute__((ext_vector_type(8))) short bf16x8;
typedef __attribute__((ext_vector_type(4))) float f32x4;

#define NBLK 512
#define NTHR 512    // 8 waves; 1 block/CU (128 KB LDS)
#define NT   32     // 32-row tiles per block: 512*32*32 = 524288 rows
#define DOUT 128

__device__ __forceinline__ unsigned short bf_rne(float x) {
  unsigned u = __builtin_bit_cast(unsigned, x);
  return (unsigned short)((u + 0x7FFFu + ((u >> 16) & 1u)) >> 16);
}
// fp32 -> bf16 hi (truncate) + bf16 lo (RNE of residual); x ~ hi+lo to ~2^-15 rel
__device__ __forceinline__ void split2(float x, short& hi, short& lo) {
  unsigned u = __builtin_bit_cast(unsigned, x);
  float hf = __builtin_bit_cast(float, u & 0xFFFF0000u);
  hi = (short)(unsigned short)(u >> 16);
  lo = (short)bf_rne(x - hf);
}

// async global->LDS, 16B/lane, per-lane global src + wave-uniform LDS base
__device__ __forceinline__ void gll16(const float* g, char* l) {
  __builtin_amdgcn_global_load_lds(
      (const __attribute__((address_space(1))) unsigned int*)g,
      (__attribute__((address_space(3))) unsigned int*)l, 16, 0, 0);
}

// R13: flight depth moved off the register file (R8-R12 law: reg-prefetch caps
// at 4KB/CU in flight -> 2.5-2.8 TB/s; spills whenever body >128 VGPR).
// x fp32 tiles DMA'd via global_load_lds into an LDS ring (8KB/wave in flight,
// ZERO VGPR cost). Each wave stages & splits ITS OWN 4 rows (per-wave vmcnt
// is a full sync for them). Counted vmcnt(6) per iter — never 0 (T4).
// LDS: F0/F1 fp32 tiles (2x32KB) + B16 bf16 hi/lo frag buffers (2x32KB).
// Frag-linear + slot^ks XOR: writes AND reads at the wave64 inherent minimum.
// W masked/split in 32 VGPRs/wave (R2-proven). (512,2): cap 128, body ~85.
__global__ __launch_bounds__(NTHR, 2)
void dagmm(const float* __restrict__ x0, const float* __restrict__ x1,
           const float* __restrict__ w0, const float* __restrict__ w1,
           const float* __restrict__ m0, const float* __restrict__ m1,
           float* __restrict__ out)
{
  __shared__ __align__(16) char L[131072];
  // F(r)  = r*32768            : fp32 tile [32 rows][256 floats], row-major
  // BH(r) = 65536 + r*32768    : bf16-hi frags, 16 frags x 1KB
  // BL(r) = BH(r) + 16384      : bf16-lo frags

  const int t   = threadIdx.x;
  const int l   = t & 63;
  const int w   = t >> 6;       // wave 0..7 -> owns output cols [w*16, w*16+16)
  const int l16 = l & 15;
  const int lq  = l >> 4;

  // ---------- W preamble: masked + hi/lo-split A-frags in VGPRs ----------
  // lane: A-row(=out col) = w*16+l16, k = ks*32 + lq*8 + j
  bf16x8 bhi[8], blo[8];
  {
    const int col = w * 16 + l16;
#pragma unroll
    for (int ks = 0; ks < 8; ++ks) {
      const int k0 = ks * 32 + lq * 8;            // never straddles 128
      const float* wp = (k0 < 128) ? (w0 + col * 128 + k0) : (w1 + col * 128 + (k0 - 128));
      const float* mp = (k0 < 128) ? (m0 + col * 128 + k0) : (m1 + col * 128 + (k0 - 128));
      float4 wa = *(const float4*)wp, wb = *(const float4*)(wp + 4);
      float4 ma = *(const float4*)mp, mb = *(const float4*)(mp + 4);
      float v[8] = {wa.x*ma.x, wa.y*ma.y, wa.z*ma.z, wa.w*ma.w,
                    wb.x*mb.x, wb.y*mb.y, wb.z*mb.z, wb.w*mb.w};
      bf16x8 hv, lv;
#pragma unroll
      for (int j = 0; j < 8; ++j) { short h, lo2; split2(v[j], h, lo2); hv[j] = h; lv[j] = lo2; }
      bhi[ks] = hv; blo[ks] = lv;
    }
  }

  const size_t Tbase = (size_t)blockIdx.x * (NT * 32);   // first batch row

  // per-lane global source: lane covers floats [l*4, l*4+4) of a row
  // (l<32 -> x0 k=l*4 ; l>=32 -> x1 k=(l-32)*4); row-major [row][256] in F
  const float* xsrc = (l < 32) ? (x0 + l * 4) : (x1 + (l - 32) * 4);

  // issue one 32-row tile ts into ring slot r: wave w stages rows w*4..w*4+3
#define ISSUE(ts, r)                                                        \
  {                                                                         \
    _Pragma("unroll")                                                       \
    for (int i = 0; i < 4; ++i) {                                           \
      const int row = w * 4 + i;                                            \
      const size_t grow = Tbase + (size_t)(ts) * 32 + row;                  \
      gll16(xsrc + grow * 128, L + (r) * 32768 + row * 1024);               \
    }                                                                       \
  }

  // ---------- prologue: tiles 0,1 in flight ----------
  ISSUE(0, 0);
  ISSUE(1, 1);
  asm volatile("s_waitcnt vmcnt(4)" ::: "memory");   // tile 0 landed (ours)

  const int rowS = w * 4 + (l >> 4);      // row this thread splits (own wave's)
  const int kf   = (l & 15) * 16;         // first of its 16 floats

  for (int tt = 0; tt < NT; ++tt) {
    const int r = tt & 1;

    // ---------- SPLIT: F[r] fp32 (own rows) -> B16[r] bf16 hi/lo ----------
    {
      const char* Fb = L + r * 32768 + rowS * 1024 + kf * 4;
      float4 v0 = ((const float4*)Fb)[0], v1 = ((const float4*)Fb)[1];
      float4 v2 = ((const float4*)Fb)[2], v3 = ((const float4*)Fb)[3];
      const int rt = rowS >> 4;
#pragma unroll
      for (int q2 = 0; q2 < 2; ++q2) {
        float vv[8];
        if (q2 == 0) { vv[0]=v0.x; vv[1]=v0.y; vv[2]=v0.z; vv[3]=v0.w;
                       vv[4]=v1.x; vv[5]=v1.y; vv[6]=v1.z; vv[7]=v1.w; }
        else         { vv[0]=v2.x; vv[1]=v2.y; vv[2]=v2.z; vv[3]=v2.w;
                       vv[4]=v3.x; vv[5]=v3.y; vv[6]=v3.z; vv[7]=v3.w; }
        const int u  = (l & 15) * 2 + q2;       // 8-float group 0..31
        const int ks = u >> 2, kq = u & 3;
        const int f  = rt * 8 + ks;
        const int slot = (kq * 16 + (rowS & 15)) ^ ks;
        bf16x8 hv, lv;
#pragma unroll
        for (int j = 0; j < 8; ++j) { short h, lo2; split2(vv[j], h, lo2); hv[j] = h; lv[j] = lo2; }
        char* bp = L + 65536 + r * 32768 + f * 1024 + slot * 16;
        *(bf16x8*)bp           = hv;
        *(bf16x8*)(bp + 16384) = lv;
      }
    }

    asm volatile("s_waitcnt lgkmcnt(0)" ::: "memory");
    __builtin_amdgcn_s_barrier();               // B16[r] visible to all waves
    asm volatile("" ::: "memory");

    // ---------- issue tile tt+2 into F[r] (always-issue; clamped tail) ----
    {
      const int ts = (tt + 2 < NT) ? (tt + 2) : (NT - 1);
      ISSUE(ts, r);
    }
    asm volatile("" ::: "memory");              // pin stores after the issue

    // ---------- MFMA: 2 rt x 8 ks x 3 terms from B16[r] ----------
    f32x4 acc[2];
    acc[0] = (f32x4){0.f, 0.f, 0.f, 0.f};
    acc[1] = (f32x4){0.f, 0.f, 0.f, 0.f};
#pragma unroll
    for (int ks = 0; ks < 8; ++ks) {
#pragma unroll
      for (int rt = 0; rt < 2; ++rt) {
        const char* bp = L + 65536 + r * 32768 + (rt * 8 + ks) * 1024 + ((l ^ ks) << 4);
        bf16x8 xh = *(const bf16x8*)bp;
        bf16x8 xl = *(const bf16x8*)(bp + 16384);
        // W ~ bhi+blo, X ~ xh+xl: 3 terms (drop blo*xl ~2^-30)
        acc[rt] = __builtin_amdgcn_mfma_f32_16x16x32_bf16(bhi[ks], xh, acc[rt], 0, 0, 0);
        acc[rt] = __builtin_amdgcn_mfma_f32_16x16x32_bf16(bhi[ks], xl, acc[rt], 0, 0, 0);
        acc[rt] = __builtin_amdgcn_mfma_f32_16x16x32_bf16(blo[ks], xh, acc[rt], 0, 0, 0);
      }
    }

    // D (R10-verified): col(l16)=x-row, lq*4+r = out col -> f32x4 stores
#pragma unroll
    for (int rt = 0; rt < 2; ++rt) {
      const size_t row = Tbase + (size_t)tt * 32 + rt * 16 + l16;
      *(f32x4*)&out[row * DOUT + w * 16 + lq * 4] = acc[rt];
    }

    // ---------- counted wait: tile tt+1 landed; loads for tt+2 in flight ---
    asm volatile("s_waitcnt vmcnt(6)" ::: "memory");
    __builtin_amdgcn_s_barrier();
    asm volatile("" ::: "memory");
  }
#undef ISSUE
}

extern "C" void kernel_launch(void* const* d_in, const int* in_sizes, int n_in,
                              void* d_out, int out_size, void* d_ws, size_t ws_size,
                              hipStream_t stream) {
  const float* x0 = (const float*)d_in[0];
  const float* x1 = (const float*)d_in[1];
  const float* w0 = (const float*)d_in[2];
  const float* w1 = (const float*)d_in[3];
  const float* m0 = (const float*)d_in[4];
  const float* m1 = (const float*)d_in[5];
  dagmm<<<NBLK, NTHR, 0, stream>>>(x0, x1, w0, w1, m0, m1, (float*)d_out);
}